// Round 1
// baseline (189.940 us; speedup 1.0000x reference)
//
#include <hip/hip_runtime.h>

// Problem constants (fixed by reference)
#define CI    16
#define CO    16
#define HID   256
#define KPAD  288    // 256 + 32; k==256 row carries b2 (VALU-free bias), rest 0
#define NKK   9      // KPAD/32 MFMA K-steps (B side; W2b layout)
#define NKH   8      // kk frags held in LDS (kk=8 pad frag synthesized in regs)
#define NCH   144    // CI*9 columns per output channel
#define IMGH  128
#define IMGW  128
#define RSTR  68     // shPatch row stride in SHORTS (136 B: 8B-aligned, phase-conflict-free)
#define KKSTR (NCH * 32)        // shorts per kk block  = 4608
#define OSTRS (NKK * NCH * 32)  // shorts per o         = 41472

typedef float f32x4  __attribute__((ext_vector_type(4)));
typedef float f32x2  __attribute__((ext_vector_type(2)));
typedef short bf16x8 __attribute__((ext_vector_type(8)));

__device__ __host__ __forceinline__ short f2bf(float f) {
  union { float f; unsigned u; } c; c.f = f;
  unsigned b = c.u + 0x7FFFu + ((c.u >> 16) & 1u);   // RNE
  return (short)(b >> 16);
}

// ---------------------------------------------------------------------------
// Prep: W2 [256][2304] fp32 (+ b2[2304]) -> W2b [o][kk:9][n':144][k:32] bf16,
// K padded to 288 (row 256 = b2, rows 257..287 = 0).
// v13: n-columns permuted dx-MAJOR: n' = dx*48 + i*3 + dyr. This makes dx
// uniform per 16-wide n-tile (tiles 0-2: dx=0, 3-5: dx=1, 6-8: dx=2), so the
// main kernel's patch contraction reads an aligned window with a per-pass
// constant shift. The final contraction sums over n, so order is free.
// grid = 36 col-blocks * 9 kk = 324 blocks x 256 threads.
// ---------------------------------------------------------------------------
__global__ void prep_w2(const float* __restrict__ W2, const float* __restrict__ b2,
                        short* __restrict__ W2b) {
  __shared__ float tile[32][65];
  const int kk = blockIdx.x % NKK;
  const int colbase = (blockIdx.x / NKK) * 64;
  const int tid = threadIdx.x;

  for (int e = tid; e < 2048; e += 256) {
    int klr = e >> 6;          // 0..31
    int cc  = e & 63;
    int col = colbase + cc;
    float v;
    if (kk < 8) v = W2[(kk * 32 + klr) * (CO * NCH) + col];
    else        v = (klr == 0) ? b2[col] : 0.f;
    tile[klr][cc] = v;
  }
  __syncthreads();
  for (int e = tid; e < 2048; e += 256) {
    int cc = e >> 5;           // 0..63
    int kl = e & 31;
    int col = colbase + cc;
    int o = col / NCH;
    int n = col - o * NCH;
    int i = n / 9, q = n - i * 9;
    int dyr = q / 3, dx = q - dyr * 3;
    int np = dx * 48 + i * 3 + dyr;            // dx-major permutation
    W2b[(((o * NKK + kk) * NCH + np) << 5) + kl] = f2bf(tile[kl][cc]);
  }
}

// ---------------------------------------------------------------------------
// Main fused kernel, v13 = v12 (128.5 us main) + patch-row LDS diet for
// 4 blocks/CU:
//  (a) shPatchT [144][68] (9 shifted copies of the same rows, 19.6 KB) ->
//      shPatch [48][68] reflect-extended raw rows (16 ci x 3 y x 66 px,
//      bf16, 6.5 KB). Total LDS 38.4 KB < 40 KB -> 4 blocks/CU = 16 waves
//      (was 3/12), and grid 1024 = exactly 4/CU -> no ragged tail round.
//  (b) W2b columns are dx-major (see prep_w2), so the contraction needs
//      row[px + dx] with dx == pass (wave-uniform): two aligned LDS reads
//      (b64 + b32) + two uniform 64-bit shifts recover the 4 taps.
//  (c) patch setup drops 9216 -> 3168 coalesced global loads.
// One block = 64 px of one image row; 4 waves; wave w owns channels
// {w, w+4, w+8, w+12}; M=64/wave, N=144/channel in 3 passes of 3 n-tiles,
// K=288 (b2 as K-row). Copy-free 2-buffer ping-pong B prefetch.
// P[16] accumulates across passes; ONE reduce-scatter tree per oj.
// grid = 4 batches * 128 rows * 2 half-rows = 1024 blocks x 256 threads.
// ---------------------------------------------------------------------------
__global__ __launch_bounds__(256, 4)
void ngconv_main(const float* __restrict__ in, const float* __restrict__ foa,
                 const float* __restrict__ W1, const float* __restrict__ b1,
                 const short* __restrict__ W2b, float* __restrict__ out) {
  __shared__ short shHf[32 * 512];        // 32 frags (ms,kk 0..7) = 32.8 KB
  __shared__ short shPatch[48 * RSTR];    // raw rows [i*3+dyr][xx] bf16, 6.5 KB

  const int tid  = threadIdx.x;
  const int lane = tid & 63;
  const int wv   = tid >> 6;
  const int c15  = lane & 15;
  const int quad = lane >> 4;

  const int blk = blockIdx.x;
  const int b   = blk >> 8;
  const int rem = blk & 255;
  const int y   = rem >> 1;
  const int x0  = (rem & 1) << 6;

  const float fx  = foa[b * 2 + 0];
  const float fy  = foa[b * 2 + 1];
  const float dyv = (float)y - fy;

  const int ry0 = (y == 0) ? 1 : (y - 1);
  const int ry2 = (y == IMGH - 1) ? (IMGH - 2) : (y + 1);

  // ---- shPatch[r=i*3+dyr][xx]: reflect-extended row, xx in [0,66) maps to
  // image x = x0 + xx - 1. Patch value for (n'=(dx,i,dyr), px) = row[px+dx].
  for (int e = tid; e < 48 * 66; e += 256) {
    int r  = e / 66;                  // 0..47 = i*3 + dyr
    int xx = e - r * 66;
    int i = r / 3, dyr = r - i * 3;
    int ryr = (dyr == 0) ? ry0 : ((dyr == 1) ? y : ry2);
    int x = x0 + xx - 1;
    x = (x < 0) ? 1 : ((x > IMGW - 1) ? (IMGW - 2) : x);   // reflect
    shPatch[r * RSTR + xx] = f2bf(in[((b * CI + i) * IMGH + ryr) * IMGW + x]);
  }

  // ---- shHf: H in fragment order, kk=0..7 only. frag(ms,kk) = A[16px][32k];
  // lane slot (c15=px, quad=k-octet). 64 px x 32 k-slots = 2048 = 8 exact its.
  for (int g = tid; g < 64 * 32; g += 256) {
    int px = g & 63;
    int ks = g >> 6;                  // 0..31 -> k0 = ks*8 < 256
    int k0 = ks << 3;
    float dxv = (float)(x0 + px) - fx;
    short hv[8];
    #pragma unroll
    for (int j = 0; j < 8; ++j) {
      int k = k0 + j;
      float h = fmaxf(fmaf(dxv, W1[k], fmaf(dyv, W1[HID + k], b1[k])), 0.f);
      hv[j] = f2bf(h);
    }
    int ms = px >> 4;
    int kk = k0 >> 5;
    int lslot = ((k0 & 31) >> 3) * 16 + (px & 15);   // quad*16 + c15
    *(bf16x8*)&shHf[((ms * NKH + kk) << 9) + (lslot << 3)] = *(bf16x8*)hv;
  }

  // ---- kk=8 pad fragment, constant, in registers: k=256 -> 1.0 (b2 row)
  bf16x8 af8 = (bf16x8){0, 0, 0, 0, 0, 0, 0, 0};
  if (quad == 0) af8[0] = (short)0x3F80;   // bf16 1.0

  __syncthreads();

  // ---- main loop: 4 output channels per wave, N in three passes of 3
  #pragma unroll 1
  for (int oj = 0; oj < 4; ++oj) {
    const int o = wv + oj * 4;
    const short* Bo = W2b + o * OSTRS + (c15 << 5) + (quad << 3);

    // per-oj partial sums (accumulate across all 3 passes; tree at the end)
    f32x2 P2[8];
    #pragma unroll
    for (int t = 0; t < 8; ++t) P2[t] = (f32x2){0.f, 0.f};

    #pragma unroll 1
    for (int pass = 0; pass < 3; ++pass) {
      const short* Bp = Bo + (pass * 3) * 512;   // first n-tile of this pass
      f32x4 acc[4][3];
      #pragma unroll
      for (int ms = 0; ms < 4; ++ms)
        #pragma unroll
        for (int j = 0; j < 3; ++j)
          acc[ms][j] = (f32x4){0.f, 0.f, 0.f, 0.f};

      // copy-free 2-buffer ping-pong, distance-1 prefetch, explicit tail.
      bf16x8 bE[3], bO[3];
      #pragma unroll
      for (int j = 0; j < 3; ++j) bE[j] = *(const bf16x8*)&Bp[j << 9];

      #pragma unroll 1
      for (int t = 0; t < 4; ++t) {
        const int kkE = 2 * t;            // even kk, uses bE
        #pragma unroll
        for (int j = 0; j < 3; ++j)       // prefetch odd kk into bO
          bO[j] = *(const bf16x8*)&Bp[(kkE + 1) * KKSTR + (j << 9)];
        {
          const short* hp = shHf + (kkE << 9) + (lane << 3);
          #pragma unroll
          for (int ms = 0; ms < 4; ++ms) {
            bf16x8 af = *(const bf16x8*)&hp[ms * (NKH << 9)];
            #pragma unroll
            for (int j = 0; j < 3; ++j)
              acc[ms][j] = __builtin_amdgcn_mfma_f32_16x16x32_bf16(
                  af, bE[j], acc[ms][j], 0, 0, 0);
          }
        }
        #pragma unroll
        for (int j = 0; j < 3; ++j)       // prefetch next even kk into bE
          bE[j] = *(const bf16x8*)&Bp[(kkE + 2) * KKSTR + (j << 9)];
        {
          const short* hp = shHf + ((kkE + 1) << 9) + (lane << 3);
          #pragma unroll
          for (int ms = 0; ms < 4; ++ms) {
            bf16x8 af = *(const bf16x8*)&hp[ms * (NKH << 9)];
            #pragma unroll
            for (int j = 0; j < 3; ++j)
              acc[ms][j] = __builtin_amdgcn_mfma_f32_16x16x32_bf16(
                  af, bO[j], acc[ms][j], 0, 0, 0);
          }
        }
      }
      {   // tail kk=8 (b2 K-row): af8 from registers, B already in bE
        #pragma unroll
        for (int ms = 0; ms < 4; ++ms)
          #pragma unroll
          for (int j = 0; j < 3; ++j)
            acc[ms][j] = __builtin_amdgcn_mfma_f32_16x16x32_bf16(
                af8, bE[j], acc[ms][j], 0, 0, 0);
      }

      // ---- per-pass patch contraction into P2 (b2 already in acc).
      // n' = (pass*3+j)*16 + c15 is dx-major: dx == pass (wave-uniform),
      // row index = 16*j + c15, window = row[px+dx .. px+dx+3].
      // Aligned reads (b64 + b32) + two uniform 64-bit shifts.
      const int sh = pass << 4;          // 0 / 16 / 32 bits
      #pragma unroll
      for (int j = 0; j < 3; ++j) {
        const short* prow = &shPatch[((j << 4) + c15) * RSTR + (quad << 2)];
        #pragma unroll
        for (int ms = 0; ms < 4; ++ms) {
          uint2 u0 = *(const uint2*)&prow[ms * 16];          // ds_read_b64
          unsigned u1 = *(const unsigned*)&prow[ms * 16 + 4]; // ds_read_b32
          unsigned long long a0 =
              (unsigned long long)u0.x | ((unsigned long long)u0.y << 32);
          unsigned long long a1 =
              (unsigned long long)u0.y | ((unsigned long long)u1 << 32);
          unsigned d0 = (unsigned)(a0 >> sh);                // taps r=0,1
          unsigned d1 = (unsigned)(a1 >> sh);                // taps r=2,3
          float p0 = __uint_as_float(d0 << 16);
          float p1 = __uint_as_float(d0 & 0xFFFF0000u);
          float p2 = __uint_as_float(d1 << 16);
          float p3 = __uint_as_float(d1 & 0xFFFF0000u);
          f32x2 a01 = {acc[ms][j][0], acc[ms][j][1]};
          f32x2 a23 = {acc[ms][j][2], acc[ms][j][3]};
          P2[ms * 2 + 0] += a01 * (f32x2){p0, p1};           // v_pk_fma_f32
          P2[ms * 2 + 1] += a23 * (f32x2){p2, p3};
        }
      }
    }

    // ---- ONE reduce-scatter tree per oj.
    // final P[0] at lane = column sum for px=(c15>>2)*16+quad*4+(c15&3)
    float P[16];
    #pragma unroll
    for (int t = 0; t < 16; ++t) P[t] = P2[t >> 1][t & 1];
    #pragma unroll
    for (int m = 8; m >= 1; m >>= 1) {
      const bool hi = (c15 & m) != 0;
      #pragma unroll
      for (int j = 0; j < m; ++j) {
        float keep = hi ? P[j + m] : P[j];
        float send = hi ? P[j] : P[j + m];
        float recv = __shfl_xor(send, m, 64);
        P[j] = keep + recv;
      }
    }

    const int x = x0 + (c15 >> 2) * 16 + quad * 4 + (c15 & 3);
    out[((b * CO + o) * IMGH + y) * IMGW + x] = P[0];
  }
}

// ---------------------------------------------------------------------------
extern "C" void kernel_launch(void* const* d_in, const int* in_sizes, int n_in,
                              void* d_out, int out_size, void* d_ws, size_t ws_size,
                              hipStream_t stream) {
  const float* in  = (const float*)d_in[0];   // [4,16,128,128]
  const float* foa = (const float*)d_in[1];   // [4,2]
  const float* W1  = (const float*)d_in[2];   // [2,256]
  const float* b1  = (const float*)d_in[3];   // [256]
  const float* W2  = (const float*)d_in[4];   // [256,2304]
  const float* b2  = (const float*)d_in[5];   // [2304]
  float* out = (float*)d_out;
  short* W2b = (short*)d_ws;                  // 16*9*144*32 bf16 = 1.33 MB

  prep_w2<<<324, 256, 0, stream>>>(W2, b2, W2b);
  ngconv_main<<<1024, 256, 0, stream>>>(in, foa, W1, b1, W2b, out);
}

// Round 2
// 155.773 us; speedup vs baseline: 1.2193x; 1.2193x over previous
//
#include <hip/hip_runtime.h>

// Problem constants (fixed by reference)
#define CI    16
#define CO    16
#define HID   256
#define KPAD  288    // 256 + 32; k==256 row carries b2 (VALU-free bias), rest 0
#define NKK   9      // KPAD/32 MFMA K-steps (B side; W2b layout)
#define NKH   8      // kk frags held in LDS (kk=8 pad frag synthesized in regs)
#define NCH   144    // CI*9 columns per output channel
#define IMGH  128
#define IMGW  128
#define NMS   8      // M=128 px per block -> 8 ms-tiles of 16
#define RSTR  132    // shPatch row stride in SHORTS (264 B, 8B-aligned, dword-stride 66 ≡ 2 mod 32)
#define RLEN  130    // valid window px per row: 128 + 2 halo
#define KKSTR (NCH * 32)        // shorts per kk block  = 4608
#define OSTRS (NKK * NCH * 32)  // shorts per o         = 41472

typedef float f32x4  __attribute__((ext_vector_type(4)));
typedef float f32x2  __attribute__((ext_vector_type(2)));
typedef short bf16x8 __attribute__((ext_vector_type(8)));

__device__ __host__ __forceinline__ short f2bf(float f) {
  union { float f; unsigned u; } c; c.f = f;
  unsigned b = c.u + 0x7FFFu + ((c.u >> 16) & 1u);   // RNE
  return (short)(b >> 16);
}

// ---------------------------------------------------------------------------
// Prep: W2 [256][2304] fp32 (+ b2[2304]) -> W2b [o][kk:9][n':144][k:32] bf16,
// K padded to 288 (row 256 = b2, rows 257..287 = 0).
// n-columns permuted dx-MAJOR: n' = dx*48 + i*3 + dyr -> dx is uniform per
// 16-wide n-tile, so the main kernel's patch contraction reads an aligned
// window with a per-pass constant shift. Contraction sums over n: order free.
// grid = 36 col-blocks * 9 kk = 324 blocks x 256 threads.
// ---------------------------------------------------------------------------
__global__ void prep_w2(const float* __restrict__ W2, const float* __restrict__ b2,
                        short* __restrict__ W2b) {
  __shared__ float tile[32][65];
  const int kk = blockIdx.x % NKK;
  const int colbase = (blockIdx.x / NKK) * 64;
  const int tid = threadIdx.x;

  for (int e = tid; e < 2048; e += 256) {
    int klr = e >> 6;          // 0..31
    int cc  = e & 63;
    int col = colbase + cc;
    float v;
    if (kk < 8) v = W2[(kk * 32 + klr) * (CO * NCH) + col];
    else        v = (klr == 0) ? b2[col] : 0.f;
    tile[klr][cc] = v;
  }
  __syncthreads();
  for (int e = tid; e < 2048; e += 256) {
    int cc = e >> 5;           // 0..63
    int kl = e & 31;
    int col = colbase + cc;
    int o = col / NCH;
    int n = col - o * NCH;
    int i = n / 9, q = n - i * 9;
    int dyr = q / 3, dx = q - dyr * 3;
    int np = dx * 48 + i * 3 + dyr;            // dx-major permutation
    W2b[(((o * NKK + kk) * NCH + np) << 5) + kl] = f2bf(tile[kl][cc]);
  }
}

// ---------------------------------------------------------------------------
// Main fused kernel, v14: M=128 (one FULL image row per block), grid 512.
// Post-mortem of v13 (4 blk/CU, 135 us, MfmaUtil 26): occupancy was NOT the
// lever — the kernel is per-wave latency-bound on the W2b B-stream, and each
// block redundantly reads the whole 1.33 MB W2b for only 64 px (1.36 GB of
// L2 traffic; FETCH blew up 14->59 MB as concurrency thrashed L2).
// M=128 halves B traffic (680 MB), doubles the MFMA burst per B-fetch
// (24 MFMA ≈ 470 matrix-pipe cycles of prefetch cover), and shrinks the
// per-XCD live footprint (2 blk/CU) so W2b stays L2-resident.
// LDS: shHf 64 frags = 65.5 KB + shPatch 12.7 KB = 78.2 KB -> 2 blocks/CU,
// grid 512 = exactly 2/CU, no ragged tail. acc[8][3] -> AGPRs.
// One block = 128 px of one image row; 4 waves; wave w owns channels
// {w, w+4, w+8, w+12}; M=128/wave (8 ms-tiles), N=144/channel in 3 passes
// of 3 n-tiles, K=288 (b2 as K-row). Copy-free 2-buffer ping-pong B prefetch.
// P2[16] accumulates across passes; TWO reduce-scatter trees per oj (2 halves).
// grid = 4 batches * 128 rows = 512 blocks x 256 threads.
// ---------------------------------------------------------------------------
__global__ __launch_bounds__(256, 2)
void ngconv_main(const float* __restrict__ in, const float* __restrict__ foa,
                 const float* __restrict__ W1, const float* __restrict__ b1,
                 const short* __restrict__ W2b, float* __restrict__ out) {
  __shared__ short shHf[64 * 512];        // 64 frags (ms 0..7, kk 0..7) = 65.5 KB
  __shared__ short shPatch[48 * RSTR];    // raw rows [i*3+dyr][xx] bf16, 12.7 KB

  const int tid  = threadIdx.x;
  const int lane = tid & 63;
  const int wv   = tid >> 6;
  const int c15  = lane & 15;
  const int quad = lane >> 4;

  const int blk = blockIdx.x;
  const int b   = blk >> 7;
  const int y   = blk & 127;

  const float fx  = foa[b * 2 + 0];
  const float fy  = foa[b * 2 + 1];
  const float dyv = (float)y - fy;

  const int ry0 = (y == 0) ? 1 : (y - 1);
  const int ry2 = (y == IMGH - 1) ? (IMGH - 2) : (y + 1);

  // ---- shPatch[r=i*3+dyr][xx]: reflect-extended row, xx in [0,130) maps to
  // image x = xx - 1. Patch value for (n'=(dx,i,dyr), px) = row[px+dx].
  for (int e = tid; e < 48 * RLEN; e += 256) {
    int r  = e / RLEN;                // 0..47 = i*3 + dyr
    int xx = e - r * RLEN;
    int i = r / 3, dyr = r - i * 3;
    int ryr = (dyr == 0) ? ry0 : ((dyr == 1) ? y : ry2);
    int x = xx - 1;
    x = (x < 0) ? 1 : ((x > IMGW - 1) ? (IMGW - 2) : x);   // reflect
    shPatch[r * RSTR + xx] = f2bf(in[((b * CI + i) * IMGH + ryr) * IMGW + x]);
  }

  // ---- shHf: H in fragment order, kk=0..7. frag(ms,kk) = A[16px][32k];
  // lane slot (c15=px, quad=k-octet). 128 px x 32 k-slots = 4096 = 16 exact its.
  for (int g = tid; g < 128 * 32; g += 256) {
    int px = g & 127;
    int ks = g >> 7;                  // 0..31 -> k0 = ks*8 < 256
    int k0 = ks << 3;
    float dxv = (float)px - fx;
    short hv[8];
    #pragma unroll
    for (int j = 0; j < 8; ++j) {
      int k = k0 + j;
      float h = fmaxf(fmaf(dxv, W1[k], fmaf(dyv, W1[HID + k], b1[k])), 0.f);
      hv[j] = f2bf(h);
    }
    int ms = px >> 4;                 // 0..7
    int kk = k0 >> 5;
    int lslot = ((k0 & 31) >> 3) * 16 + (px & 15);   // quad*16 + c15
    *(bf16x8*)&shHf[((ms * NKH + kk) << 9) + (lslot << 3)] = *(bf16x8*)hv;
  }

  // ---- kk=8 pad fragment, constant, in registers: k=256 -> 1.0 (b2 row)
  bf16x8 af8 = (bf16x8){0, 0, 0, 0, 0, 0, 0, 0};
  if (quad == 0) af8[0] = (short)0x3F80;   // bf16 1.0

  __syncthreads();

  // ---- main loop: 4 output channels per wave, N in three passes of 3
  #pragma unroll 1
  for (int oj = 0; oj < 4; ++oj) {
    const int o = wv + oj * 4;
    const short* Bo = W2b + o * OSTRS + (c15 << 5) + (quad << 3);

    // per-oj partial sums (accumulate across all 3 passes; trees at the end)
    f32x2 P2[16];
    #pragma unroll
    for (int t = 0; t < 16; ++t) P2[t] = (f32x2){0.f, 0.f};

    #pragma unroll 1
    for (int pass = 0; pass < 3; ++pass) {
      const short* Bp = Bo + (pass * 3) * 512;   // first n-tile of this pass
      f32x4 acc[NMS][3];
      #pragma unroll
      for (int ms = 0; ms < NMS; ++ms)
        #pragma unroll
        for (int j = 0; j < 3; ++j)
          acc[ms][j] = (f32x4){0.f, 0.f, 0.f, 0.f};

      // copy-free 2-buffer ping-pong, distance-1 prefetch, explicit tail.
      bf16x8 bE[3], bO[3];
      #pragma unroll
      for (int j = 0; j < 3; ++j) bE[j] = *(const bf16x8*)&Bp[j << 9];

      #pragma unroll 1
      for (int t = 0; t < 4; ++t) {
        const int kkE = 2 * t;            // even kk, uses bE
        #pragma unroll
        for (int j = 0; j < 3; ++j)       // prefetch odd kk into bO
          bO[j] = *(const bf16x8*)&Bp[(kkE + 1) * KKSTR + (j << 9)];
        {
          const short* hp = shHf + (kkE << 9) + (lane << 3);
          #pragma unroll
          for (int ms = 0; ms < NMS; ++ms) {
            bf16x8 af = *(const bf16x8*)&hp[ms * (NKH << 9)];
            #pragma unroll
            for (int j = 0; j < 3; ++j)
              acc[ms][j] = __builtin_amdgcn_mfma_f32_16x16x32_bf16(
                  af, bE[j], acc[ms][j], 0, 0, 0);
          }
        }
        #pragma unroll
        for (int j = 0; j < 3; ++j)       // prefetch next even kk into bE
          bE[j] = *(const bf16x8*)&Bp[(kkE + 2) * KKSTR + (j << 9)];
        {
          const short* hp = shHf + ((kkE + 1) << 9) + (lane << 3);
          #pragma unroll
          for (int ms = 0; ms < NMS; ++ms) {
            bf16x8 af = *(const bf16x8*)&hp[ms * (NKH << 9)];
            #pragma unroll
            for (int j = 0; j < 3; ++j)
              acc[ms][j] = __builtin_amdgcn_mfma_f32_16x16x32_bf16(
                  af, bO[j], acc[ms][j], 0, 0, 0);
          }
        }
      }
      {   // tail kk=8 (b2 K-row): af8 from registers, B already in bE
        #pragma unroll
        for (int ms = 0; ms < NMS; ++ms)
          #pragma unroll
          for (int j = 0; j < 3; ++j)
            acc[ms][j] = __builtin_amdgcn_mfma_f32_16x16x32_bf16(
                af8, bE[j], acc[ms][j], 0, 0, 0);
      }

      // ---- per-pass patch contraction into P2 (b2 already in acc).
      // n' = (pass*3+j)*16 + c15 is dx-major: dx == pass (wave-uniform),
      // row index = 16*j + c15, window = row[px+dx .. px+dx+3].
      // Aligned reads (b64 + b32) + two uniform 64-bit shifts.
      const int sh = pass << 4;          // 0 / 16 / 32 bits
      #pragma unroll
      for (int j = 0; j < 3; ++j) {
        const short* prow = &shPatch[((j << 4) + c15) * RSTR + (quad << 2)];
        #pragma unroll
        for (int ms = 0; ms < NMS; ++ms) {
          uint2 u0 = *(const uint2*)&prow[ms * 16];           // ds_read_b64
          unsigned u1 = *(const unsigned*)&prow[ms * 16 + 4]; // ds_read_b32
          unsigned long long a0 =
              (unsigned long long)u0.x | ((unsigned long long)u0.y << 32);
          unsigned long long a1 =
              (unsigned long long)u0.y | ((unsigned long long)u1 << 32);
          unsigned d0 = (unsigned)(a0 >> sh);                // taps r=0,1
          unsigned d1 = (unsigned)(a1 >> sh);                // taps r=2,3
          float p0 = __uint_as_float(d0 << 16);
          float p1 = __uint_as_float(d0 & 0xFFFF0000u);
          float p2 = __uint_as_float(d1 << 16);
          float p3 = __uint_as_float(d1 & 0xFFFF0000u);
          f32x2 a01 = {acc[ms][j][0], acc[ms][j][1]};
          f32x2 a23 = {acc[ms][j][2], acc[ms][j][3]};
          P2[ms * 2 + 0] += a01 * (f32x2){p0, p1};           // v_pk_fma_f32
          P2[ms * 2 + 1] += a23 * (f32x2){p2, p3};
        }
      }
    }

    // ---- TWO reduce-scatter trees per oj (ms 0..3 -> px 0..63; 4..7 -> 64..127).
    // final P[0] at lane = column sum for px = half*64 + (c15>>2)*16 + quad*4 + (c15&3)
    #pragma unroll
    for (int half = 0; half < 2; ++half) {
      float P[16];
      #pragma unroll
      for (int t = 0; t < 16; ++t) P[t] = P2[half * 8 + (t >> 1)][t & 1];
      #pragma unroll
      for (int m = 8; m >= 1; m >>= 1) {
        const bool hi = (c15 & m) != 0;
        #pragma unroll
        for (int j = 0; j < m; ++j) {
          float keep = hi ? P[j + m] : P[j];
          float send = hi ? P[j] : P[j + m];
          float recv = __shfl_xor(send, m, 64);
          P[j] = keep + recv;
        }
      }
      const int x = half * 64 + (c15 >> 2) * 16 + quad * 4 + (c15 & 3);
      out[((b * CO + o) * IMGH + y) * IMGW + x] = P[0];
    }
  }
}

// ---------------------------------------------------------------------------
extern "C" void kernel_launch(void* const* d_in, const int* in_sizes, int n_in,
                              void* d_out, int out_size, void* d_ws, size_t ws_size,
                              hipStream_t stream) {
  const float* in  = (const float*)d_in[0];   // [4,16,128,128]
  const float* foa = (const float*)d_in[1];   // [4,2]
  const float* W1  = (const float*)d_in[2];   // [2,256]
  const float* b1  = (const float*)d_in[3];   // [256]
  const float* W2  = (const float*)d_in[4];   // [256,2304]
  const float* b2  = (const float*)d_in[5];   // [2304]
  float* out = (float*)d_out;
  short* W2b = (short*)d_ws;                  // 16*9*144*32 bf16 = 1.33 MB

  prep_w2<<<324, 256, 0, stream>>>(W2, b2, W2b);
  ngconv_main<<<512, 256, 0, stream>>>(in, foa, W1, b1, W2b, out);
}